// Round 1
// baseline (1688.025 us; speedup 1.0000x reference)
//
#include <hip/hip_runtime.h>
#include <hip/hip_cooperative_groups.h>

namespace cg = cooperative_groups;

#define G_ 100
#define T_ 24
#define NSC 128
#define BATCH 8
#define NITER 40
#define HALF_G 50
#define SLICES 48
#define NBLK (BATCH*SLICES)
#define NTHR 256
#define SHB 12160   // per-batch shared-var block (floats), padded

__device__ __forceinline__ float blockReduceSum(float v, float* sRed) {
#pragma unroll
  for (int off = 32; off > 0; off >>= 1) v += __shfl_down(v, off, 64);
  const int w = threadIdx.x >> 6;
  __syncthreads();
  if ((threadIdx.x & 63) == 0) sRed[w] = v;
  __syncthreads();
  return sRed[0] + sRed[1] + sRed[2] + sRed[3];
}

// monotonic-counter batch barrier (48 WGs per batch); no reset -> no init race
__device__ __forceinline__ void bbar(unsigned* cnt, unsigned target) {
  __syncthreads();
  if (threadIdx.x == 0) {
    __threadfence();                 // release
    atomicAdd(cnt, 1u);
    while (atomicAdd(cnt, 0u) < target) __builtin_amdgcn_s_sleep(8);
    __threadfence();                 // acquire
  }
  __syncthreads();
}

__global__ __launch_bounds__(NTHR, 2) void dro_kernel(
    const float* __restrict__ forecast, const float* __restrict__ omega,
    const float* __restrict__ om_min, const float* __restrict__ om_max,
    const float* __restrict__ eps_in, const float* __restrict__ pmin_g,
    const float* __restrict__ pmax_g, const float* __restrict__ bG,
    const float* __restrict__ cG, float* __restrict__ out, float* __restrict__ ws)
{
  constexpr float LR = 2e-4f, VOLL = 1000.f, VOSP = 50.f;
  constexpr float TWO_RHO = 20.f, INVN = 1.f/128.f;
  const int blk = blockIdx.x;
  const int b = blk & 7;            // batch -> XCD-affine under round-robin
  const int slice = blk >> 3;       // 0..47
  const int t_own = slice >> 1;
  const int half = slice & 1;
  const int g0 = half * HALF_G;
  const int tid = threadIdx.x;
  const int wave = tid >> 6, lane = tid & 63;

  __shared__ float sdU[NSC*HALF_G], sdD[NSC*HALF_G];   // [n][g] for own (t,half)
  __shared__ float sRu[HALF_G], sRd[HALF_G];
  __shared__ float sLS[NSC], sSP[NSC], sOm[NSC], sR2[NSC];
  __shared__ float sQn[NSC], sGQn[NSC], sDM[NSC], sDm[NSC];
  __shared__ float sB[G_], sPmin[G_], sPmax[G_], sC[G_];
  __shared__ float sAccU[4][64], sAccD[4][64];
  __shared__ float sRed[4];

  float* SH0 = ws;
  float* SH1 = ws + BATCH*SHB;
  float* QNP = ws + 2*BATCH*SHB;                 // [2][B][48][128]
  float* S2P = QNP + 2*BATCH*SLICES*NSC;         // [2][B][48][128]
  float* ST1 = S2P + 2*BATCH*SLICES*NSC;         // [B][64]
  unsigned* BAR = (unsigned*)(ST1 + BATCH*64);   // [B][16]

  // ---------------- init ----------------
  for (int i = tid; i < G_; i += NTHR) {
    sB[i] = bG[i]; sPmin[i] = pmin_g[i]; sPmax[i] = pmax_g[i]; sC[i] = cG[i];
  }
  for (int i = tid; i < NSC*HALF_G; i += NTHR) { sdU[i] = 0.f; sdD[i] = 0.f; }
  for (int i = tid; i < HALF_G; i += NTHR) { sRu[i] = 0.f; sRd[i] = 0.f; }
  for (int n = tid; n < NSC; n += NTHR) {
    sLS[n] = 0.f; sSP[n] = 0.f;
    sOm[n] = omega[(b*NSC + n)*T_ + t_own];
    float dM = 0.f, dm = 0.f;
    for (int t = 0; t < T_; ++t) {
      float o = omega[(b*NSC + n)*T_ + t];
      dM += om_max[b*T_ + t] - o;
      dm += o - om_min[b*T_ + t];
    }
    sDM[n] = dM; sDm[n] = dm;
  }
  {
    int idx = slice*NTHR + tid;
    if (idx < SHB) {
      float v = 0.f;
      if (idx < 2400) v = 0.5f*(pmin_g[idx % 100] + pmax_g[idx % 100]); // P init
      SH0[b*SHB + idx] = v;
    }
    for (int n = tid; n < NSC; n += NTHR) {
      QNP[(0*BATCH + b)*SLICES*NSC + slice*NSC + n] = 0.f;
      S2P[(0*BATCH + b)*SLICES*NSC + slice*NSC + n] = 0.f;
    }
    if (slice == 0 && tid == 0) BAR[b*16] = 0u;
  }
  cg::this_grid().sync();   // protects barrier-counter + parity-0 init

  unsigned bar_round = 0;

  for (int k = 0; k <= NITER; ++k) {
    const int cur = k & 1, nxt = cur ^ 1;
    float* Sc = (cur ? SH1 : SH0) + b*SHB;
    float* Sn = (nxt ? SH1 : SH0) + b*SHB;
    float* Pg  = Sc;          float* duM = Sc + 2400; float* ddM = Sc + 4800;
    float* dum = Sc + 7200;   float* ddm = Sc + 9600;
    float* LSM = Sc + 12000;  float* SPM = Sc + 12024;
    float* LSm = Sc + 12048;  float* SPm = Sc + 12072;
    const float gamma = Sc[12096];
    const float* qnp_r = QNP + (cur*BATCH + b)*SLICES*NSC;
    const float* s2p_r = S2P + (cur*BATCH + b)*SLICES*NSC;
    float* qnp_w = QNP + (nxt*BATCH + b)*SLICES*NSC;
    float* s2p_w = S2P + (nxt*BATCH + b)*SLICES*NSC;

    // ---- consume: Qn[n], r2[n] ----
    for (int n = tid; n < NSC; n += NTHR) {
      float q = 0.f;
      for (int s = 0; s < SLICES; ++s) q += qnp_r[s*NSC + n];
      sQn[n] = q;
      float s2 = s2p_r[(t_own*2+0)*NSC + n] + s2p_r[(t_own*2+1)*NSC + n];
      sR2[n] = s2 + sLS[n] - sSP[n] - sOm[n];
    }
    // Qmax / Qmin (redundant per WG)
    float qmx = 0.f, qmn = 0.f;
    for (int p = tid; p < 2400; p += NTHR) {
      int g = p % 100;
      float bg = sB[g];
      qmx += 2.f*bg*duM[p] + 0.5f*bg*ddM[p];
      qmn += 2.f*bg*dum[p] + 0.5f*bg*ddm[p];
    }
    if (tid < T_) {
      qmx += VOLL*LSM[tid] + VOSP*SPM[tid];
      qmn += VOLL*LSm[tid] + VOSP*SPm[tid];
    }
    const float Qmax = blockReduceSum(qmx, sRed);
    const float Qmin = blockReduceSum(qmn, sRed);

    if (k == NITER) {   // -------- final: phi + outputs --------
      for (int n = tid; n < NSC; n += NTHR) {
        float m1 = Qmax - gamma*sDM[n];
        float m2 = Qmin - gamma*sDm[n];
        float ph = fmaxf(sQn[n], fmaxf(m1, m2));
        sQn[n] = ph;
        if (slice == 0) out[76800 + b*NSC + n] = ph;
      }
      float st = 0.f;
      if (tid < HALF_G) {
        int g = g0 + tid; int p = t_own*100 + g;
        float Pv = Pg[p];
        float costv = sB[g]*Pv + sC[g];
        st = costv + 0.05f*sB[g]*sRu[tid] + 0.02f*sB[g]*sRd[tid];
        int o = b*2400 + g*T_ + t_own;
        out[o] = Pv;
        out[19200 + o] = sRu[tid];
        out[38400 + o] = sRd[tid];
        out[57600 + o] = costv;
      }
      st = blockReduceSum(st, sRed);
      if (tid == 0) ST1[b*64 + slice] = st;
      if (slice == 0 && tid == 0) out[77824 + b] = gamma;
      bbar(&BAR[b*16], (++bar_round)*SLICES);
      if (slice == 0) {
        float pm = 0.f;
        for (int n = tid; n < NSC; n += NTHR) pm += sQn[n];
        pm = blockReduceSum(pm, sRed);
        float s1 = 0.f;
        for (int s = tid; s < SLICES; s += NTHR) s1 += ST1[b*64 + s];
        s1 = blockReduceSum(s1, sRed);
        if (tid == 0) out[77832 + b] = s1 + pm*INVN + eps_in[b]*gamma;
      }
      break;
    }

    // r3, r4, rP for own t (sums over all g, old parity)
    float r3p = 0.f, r4p = 0.f, rpp = 0.f;
    for (int g = tid; g < G_; g += NTHR) {
      int p = t_own*100 + g;
      r3p += duM[p] - ddM[p];
      r4p += dum[p] - ddm[p];
      rpp += Pg[p];
    }
    const float r3 = blockReduceSum(r3p, sRed) + LSM[t_own] - SPM[t_own] - om_max[b*T_ + t_own];
    const float r4 = blockReduceSum(r4p, sRed) + LSm[t_own] - SPm[t_own] - om_min[b*T_ + t_own];
    const float rP = blockReduceSum(rpp, sRed) - forecast[b*T_ + t_own];

    // phi subgradient weights (JAX balanced_eq tie rule)
    float g1l = 0.f, g2l = 0.f, sgl = 0.f;
    for (int n = tid; n < NSC; n += NTHR) {
      float Qn = sQn[n];
      float m1 = Qmax - gamma*sDM[n];
      float m2 = Qmin - gamma*sDm[n];
      float inner = fmaxf(m1, m2);
      float ph = fmaxf(Qn, inner);
      float gQn = (Qn == ph ? 1.f : 0.f) / ((inner == ph) ? 2.f : 1.f);
      float gIn = (inner == ph ? 1.f : 0.f) / ((Qn == ph) ? 2.f : 1.f);
      float gm1 = gIn * (m1 == inner ? 1.f : 0.f) / ((m2 == inner) ? 2.f : 1.f);
      float gm2 = gIn * (m2 == inner ? 1.f : 0.f) / ((m1 == inner) ? 2.f : 1.f);
      sGQn[n] = gQn;
      g1l += gm1; g2l += gm2; sgl += gm1*sDM[n] + gm2*sDm[n];
    }
    const float S1s = blockReduceSum(g1l, sRed);
    const float S2s = blockReduceSum(g2l, sRed);
    const float Sg  = blockReduceSum(sgl, sRed);

    // ---- pass A: d_up/d_dn update + sum_n relu(d-R) ----
    float accU = 0.f, accD = 0.f;
    if (lane < HALF_G) {
      const int g = g0 + lane;
      const float rtu = 2.f*sB[g], rtd = 0.5f*sB[g];
      const float ru = sRu[lane], rd = sRd[lane];
      for (int n = wave; n < NSC; n += 4) {
        const int idx = n*HALF_G + lane;
        float du = sdU[idx], dd = sdD[idx];
        float r7 = fmaxf(du - ru, 0.f);
        float r8 = fmaxf(dd - rd, 0.f);
        accU += r7; accD += r8;
        float gq = sGQn[n]*INVN;
        float r2 = sR2[n];
        float gdu = gq*rtu + TWO_RHO*( r2 + r7);
        float gdd = gq*rtd + TWO_RHO*(-r2 + r8);
        sdU[idx] = fmaxf(du - LR*gdu, 0.f);
        sdD[idx] = fmaxf(dd - LR*gdd, 0.f);
      }
    }
    sAccU[wave][lane] = accU;
    sAccD[wave][lane] = accD;
    __syncthreads();

    // ---- pass B: shared vars (write parity nxt), R_up/R_dn (LDS), LS/SP ----
    if (tid < HALF_G) {
      const int g = g0 + tid;
      const int p = t_own*100 + g;
      const float rupS = sAccU[0][tid]+sAccU[1][tid]+sAccU[2][tid]+sAccU[3][tid];
      const float rdnS = sAccD[0][tid]+sAccD[1][tid]+sAccD[2][tid]+sAccD[3][tid];
      const float Pold = Pg[p];
      const float ru = sRu[tid], rd = sRd[tid];
      const float duMo = duM[p], ddMo = ddM[p], dumo = dum[p], ddmo = ddm[p];
      const float r5  = fmaxf(Pold + ru - sPmax[g], 0.f);
      const float r6  = fmaxf(sPmin[g] - Pold + rd, 0.f);
      const float r9  = fmaxf(duMo - ru, 0.f);
      const float r10 = fmaxf(ddMo - rd, 0.f);
      const float r11 = fmaxf(dumo - ru, 0.f);
      const float r12 = fmaxf(ddmo - rd, 0.f);
      const float rampg = sPmax[g];
      float gP = sB[g] + TWO_RHO*(rP + r5 - r6);
      if (t_own > 0) {
        float dp = Pold - Pg[p - 100];
        gP += TWO_RHO*fmaxf(fabsf(dp) - rampg, 0.f)*(dp >= 0.f ? 1.f : -1.f);
      }
      if (t_own < T_-1) {
        float dq = Pg[p + 100] - Pold;
        gP -= TWO_RHO*fmaxf(fabsf(dq) - rampg, 0.f)*(dq >= 0.f ? 1.f : -1.f);
      }
      Sn[p] = fminf(fmaxf(Pold - LR*gP, sPmin[g]), sPmax[g]);
      const float rtu = 2.f*sB[g], rtd = 0.5f*sB[g];
      float gRu = 0.05f*sB[g] + TWO_RHO*(r5 - rupS - r9 - r11);
      float gRd = 0.02f*sB[g] + TWO_RHO*(r6 - rdnS - r10 - r12);
      sRu[tid] = fmaxf(ru - LR*gRu, 0.f);
      sRd[tid] = fmaxf(rd - LR*gRd, 0.f);
      Sn[2400 + p] = fmaxf(duMo - LR*(INVN*S1s*rtu + TWO_RHO*( r3 + r9 )), 0.f);
      Sn[4800 + p] = fmaxf(ddMo - LR*(INVN*S1s*rtd + TWO_RHO*(-r3 + r10)), 0.f);
      Sn[7200 + p] = fmaxf(dumo - LR*(INVN*S2s*rtu + TWO_RHO*( r4 + r11)), 0.f);
      Sn[9600 + p] = fmaxf(ddmo - LR*(INVN*S2s*rtd + TWO_RHO*(-r4 + r12)), 0.f);
    }
    for (int n = tid; n < NSC; n += NTHR) {
      float gq = sGQn[n]*INVN;
      float r2 = sR2[n];
      sLS[n] = fmaxf(sLS[n] - LR*(gq*VOLL + TWO_RHO*r2), 0.f);
      sSP[n] = fmaxf(sSP[n] - LR*(gq*VOSP - TWO_RHO*r2), 0.f);
    }
    if (tid == HALF_G) {
      if (half == 0) {
        Sn[12000 + t_own] = fmaxf(LSM[t_own] - LR*(INVN*S1s*VOLL + TWO_RHO*r3), 0.f);
        Sn[12024 + t_own] = fmaxf(SPM[t_own] - LR*(INVN*S1s*VOSP - TWO_RHO*r3), 0.f);
      } else {
        Sn[12048 + t_own] = fmaxf(LSm[t_own] - LR*(INVN*S2s*VOLL + TWO_RHO*r4), 0.f);
        Sn[12072 + t_own] = fmaxf(SPm[t_own] - LR*(INVN*S2s*VOSP - TWO_RHO*r4), 0.f);
      }
      if (slice == 0) Sn[12096] = fmaxf(gamma - LR*(eps_in[b] - INVN*Sg), 0.f);
    }
    __syncthreads();

    // ---- produce: new partials from updated state ----
    for (int n = wave; n < NSC; n += 4) {
      float qv = 0.f, sv = 0.f;
      if (lane < HALF_G) {
        const int g = g0 + lane;
        const int idx = n*HALF_G + lane;
        float du = sdU[idx], dd = sdD[idx];
        qv = 2.f*sB[g]*du + 0.5f*sB[g]*dd;
        sv = du - dd;
      }
#pragma unroll
      for (int off = 32; off > 0; off >>= 1) {
        qv += __shfl_down(qv, off, 64);
        sv += __shfl_down(sv, off, 64);
      }
      if (lane == 0) {
        if (half == 0) qv += VOLL*sLS[n] + VOSP*sSP[n];
        qnp_w[slice*NSC + n] = qv;
        s2p_w[slice*NSC + n] = sv;
      }
    }
    bbar(&BAR[b*16], (++bar_round)*SLICES);
  }
}

extern "C" void kernel_launch(void* const* d_in, const int* in_sizes, int n_in,
                              void* d_out, int out_size, void* d_ws, size_t ws_size,
                              hipStream_t stream) {
  const float* forecast = (const float*)d_in[0];
  const float* omega    = (const float*)d_in[1];
  const float* omin     = (const float*)d_in[2];
  const float* omax     = (const float*)d_in[3];
  const float* eps      = (const float*)d_in[4];
  const float* pmin     = (const float*)d_in[5];
  const float* pmax     = (const float*)d_in[6];
  const float* bG       = (const float*)d_in[7];
  const float* cG       = (const float*)d_in[8];
  float* out = (float*)d_out;
  float* ws  = (float*)d_ws;
  void* args[] = { &forecast, &omega, &omin, &omax, &eps, &pmin, &pmax, &bG, &cG, &out, &ws };
  hipLaunchCooperativeKernel((const void*)dro_kernel, dim3(NBLK), dim3(NTHR),
                             args, 0, stream);
}

// Round 2
// 1109.772 us; speedup vs baseline: 1.5211x; 1.5211x over previous
//
#include <hip/hip_runtime.h>
#include <hip/hip_cooperative_groups.h>

namespace cg = cooperative_groups;

#define G_ 100
#define T_ 24
#define NSC 128
#define BATCH 8
#define NITER 40
#define HALF_G 50
#define SLICES 48
#define NBLK (BATCH*SLICES)
#define NTHR 256

__device__ __forceinline__ float gload(const float* p){
  return __hip_atomic_load(p, __ATOMIC_RELAXED, __HIP_MEMORY_SCOPE_AGENT);
}
__device__ __forceinline__ void gstore(float* p, float v){
  __hip_atomic_store(p, v, __ATOMIC_RELAXED, __HIP_MEMORY_SCOPE_AGENT);
}

__device__ __forceinline__ void blockReduce2(float& a, float& b, float* sR){
#pragma unroll
  for (int off=32; off; off>>=1){ a+=__shfl_down(a,off,64); b+=__shfl_down(b,off,64); }
  const int w = threadIdx.x>>6;
  __syncthreads();
  if ((threadIdx.x&63)==0){ sR[w]=a; sR[4+w]=b; }
  __syncthreads();
  a = sR[0]+sR[1]+sR[2]+sR[3];
  b = sR[4]+sR[5]+sR[6]+sR[7];
}

__device__ __forceinline__ void blockReduce3(float& a, float& b, float& c, float* sR){
#pragma unroll
  for (int off=32; off; off>>=1){
    a+=__shfl_down(a,off,64); b+=__shfl_down(b,off,64); c+=__shfl_down(c,off,64);
  }
  const int w = threadIdx.x>>6;
  __syncthreads();
  if ((threadIdx.x&63)==0){ sR[w]=a; sR[4+w]=b; sR[8+w]=c; }
  __syncthreads();
  a=sR[0]+sR[1]+sR[2]+sR[3];
  b=sR[4]+sR[5]+sR[6]+sR[7];
  c=sR[8]+sR[9]+sR[10]+sR[11];
}

// monotonic-counter batch barrier; release add + relaxed-load spin (no RMW poll)
__device__ __forceinline__ void bbar(unsigned* cnt, unsigned target){
  __syncthreads();
  if (threadIdx.x==0){
    __hip_atomic_fetch_add(cnt, 1u, __ATOMIC_RELEASE, __HIP_MEMORY_SCOPE_AGENT);
    while (__hip_atomic_load(cnt, __ATOMIC_RELAXED, __HIP_MEMORY_SCOPE_AGENT) < target)
      __builtin_amdgcn_s_sleep(2);
    __builtin_amdgcn_fence(__ATOMIC_ACQUIRE, "agent");
  }
  __syncthreads();
}

__global__ __launch_bounds__(NTHR, 2) void dro_kernel(
    const float* __restrict__ forecast, const float* __restrict__ omega,
    const float* __restrict__ om_min, const float* __restrict__ om_max,
    const float* __restrict__ eps_in, const float* __restrict__ pmin_g,
    const float* __restrict__ pmax_g, const float* __restrict__ bG,
    const float* __restrict__ cG, float* __restrict__ out, float* __restrict__ ws)
{
  constexpr float LR=2e-4f, VOLL=1000.f, VOSP=50.f, TWO_RHO=20.f, INVN=1.f/128.f;
  const int blk=blockIdx.x;
  const int b=blk&7;            // consecutive blk -> round-robin XCD: batch stays on one XCD
  const int slice=blk>>3;       // 0..47
  const int t_own=slice>>1, half=slice&1, g0=half*HALF_G;
  const int tid=threadIdx.x, wave=tid>>6, lane=tid&63;

  __shared__ float sdU[NSC*HALF_G], sdD[NSC*HALF_G];
  __shared__ float sRu[HALF_G], sRd[HALF_G];
  __shared__ float sP[HALF_G], sduM[HALF_G], sddM[HALF_G], sdum[HALF_G], sddm[HALF_G];
  __shared__ float sLS[NSC], sSP[NSC], sOm[NSC], sR2[NSC];
  __shared__ float sQn[NSC], sGQn[NSC], sDM[NSC], sDm[NSC];
  __shared__ float sQnP[NTHR], sS2p[NTHR];
  __shared__ float sB[G_], sPmin[G_], sPmax[G_], sC[G_];
  __shared__ float sAccU[4][64], sAccD[4][64];
  __shared__ float sRed[12], sScal[4];
  __shared__ float sLSa, sLSb;   // (LSM,SPM) if half==0 else (LSm,SPm), own t

  // ws layout (floats)
  float* PP   = ws;                 // [2][B][T][G]   = 38400
  float* QNPb = ws + 38400;         // [2][B][48][128]= 98304   (layout [s][n])
  float* S2Pb = ws + 136704;        // [2][B][48][128]= 98304
  float* QXPb = ws + 235008;        // [2][B][48]
  float* QNQb = ws + 235776;        // [2][B][48]
  float* R3Pb = ws + 236544;        // [2][B][48]
  float* R4Pb = ws + 237312;        // [2][B][48]
  float* RPPb = ws + 238080;        // [2][B][48]
  float* GAMb = ws + 238848;        // [2][B]
  float* ST1  = ws + 238864;        // [B][64]
  unsigned* BAR = (unsigned*)(ws + 239376); // [B][16]

  // ---------------- init ----------------
  for (int i=tid;i<G_;i+=NTHR){ sB[i]=bG[i]; sPmin[i]=pmin_g[i]; sPmax[i]=pmax_g[i]; sC[i]=cG[i]; }
  for (int i=tid;i<NSC*HALF_G;i+=NTHR){ sdU[i]=0.f; sdD[i]=0.f; }
  if (tid<HALF_G){ sRu[tid]=0.f; sRd[tid]=0.f; sduM[tid]=0.f; sddM[tid]=0.f; sdum[tid]=0.f; sddm[tid]=0.f; }
  for (int n=tid;n<NSC;n+=NTHR){
    sLS[n]=0.f; sSP[n]=0.f;
    sOm[n]=omega[(b*NSC+n)*T_+t_own];
    float dM=0.f,dm=0.f;
    for (int t=0;t<T_;++t){
      float o=omega[(b*NSC+n)*T_+t];
      dM+=om_max[b*T_+t]-o; dm+=o-om_min[b*T_+t];
    }
    sDM[n]=dM; sDm[n]=dm;
  }
  if (tid==0){ sLSa=0.f; sLSb=0.f; }
  __syncthreads();

  {
    float* qnp0 = QNPb + b*6144;
    float* s2p0 = S2Pb + b*6144;
    if (tid<NSC){ gstore(&qnp0[slice*NSC+tid],0.f); gstore(&s2p0[slice*NSC+tid],0.f); }
    float p0=0.f;
    if (tid<HALF_G){
      int g=g0+tid;
      p0=0.5f*(sPmin[g]+sPmax[g]);
      sP[tid]=p0;
      gstore(&PP[b*2400 + t_own*G_ + g], p0);
    }
    if (wave==0){
      float r=p0;
#pragma unroll
      for (int off=32;off;off>>=1) r+=__shfl_down(r,off,64);
      if (lane==0){
        gstore(&RPPb[b*SLICES+slice], r);
        gstore(&QXPb[b*SLICES+slice],0.f); gstore(&QNQb[b*SLICES+slice],0.f);
        gstore(&R3Pb[b*SLICES+slice],0.f); gstore(&R4Pb[b*SLICES+slice],0.f);
      }
    }
    if (slice==0&&tid==0){ gstore(&GAMb[b],0.f); BAR[b*16]=0u; }
  }
  cg::this_grid().sync();   // protects parity-0 data + barrier counter init

  unsigned bar_round=0;

  for (int k=0;k<=NITER;++k){
    const int cur=k&1, nxt=cur^1;
    float* ppc  = PP   + (cur*BATCH+b)*2400;
    float* ppn  = PP   + (nxt*BATCH+b)*2400;
    const float* qnpc = QNPb + (cur*BATCH+b)*6144;
    float*       qnpn = QNPb + (nxt*BATCH+b)*6144;
    const float* s2pc = S2Pb + (cur*BATCH+b)*6144;
    float*       s2pn = S2Pb + (nxt*BATCH+b)*6144;
    const float* qxpc = QXPb + (cur*BATCH+b)*SLICES;
    float*       qxpn = QXPb + (nxt*BATCH+b)*SLICES;
    const float* qnqc = QNQb + (cur*BATCH+b)*SLICES;
    float*       qnqn = QNQb + (nxt*BATCH+b)*SLICES;
    const float* r3pc = R3Pb + (cur*BATCH+b)*SLICES;
    float*       r3pn = R3Pb + (nxt*BATCH+b)*SLICES;
    const float* r4pc = R4Pb + (cur*BATCH+b)*SLICES;
    float*       r4pn = R4Pb + (nxt*BATCH+b)*SLICES;
    const float* rppc = RPPb + (cur*BATCH+b)*SLICES;
    float*       rppn = RPPb + (nxt*BATCH+b)*SLICES;
    const float* gamc = GAMb + cur*BATCH + b;
    float*       gamn = GAMb + nxt*BATCH + b;

    // ---- early independent loads (hide LLC latency) ----
    float pPm1=0.f, pPp1=0.f;
    if (tid<HALF_G){
      const int g=g0+tid;
      if (t_own>0)     pPm1 = gload(&ppc[(t_own-1)*G_+g]);
      if (t_own<T_-1)  pPp1 = gload(&ppc[(t_own+1)*G_+g]);
    }
    if (tid==192) sScal[0] = gload(&r3pc[2*t_own]) + gload(&r3pc[2*t_own+1]) - om_max[b*T_+t_own];
    if (tid==193) sScal[1] = gload(&r4pc[2*t_own]) + gload(&r4pc[2*t_own+1]) - om_min[b*T_+t_own];
    if (tid==194) sScal[2] = gload(&rppc[2*t_own]) + gload(&rppc[2*t_own+1]) - forecast[b*T_+t_own];
    if (tid==195) sScal[3] = gload(gamc);

    // ---- consume: Qn partials split over all 4 waves, coalesced [s][n] ----
    {
      const int n = tid & 127, sb0 = (tid>>7)*24;
      float q=0.f;
#pragma unroll
      for (int s=0;s<24;++s) q += gload(&qnpc[(sb0+s)*NSC+n]);
      sQnP[tid]=q;
      sS2p[tid]=gload(&s2pc[(2*t_own+(tid>>7))*NSC+n]);
    }
    float Qmax = (tid<SLICES)? gload(&qxpc[tid]) : 0.f;
    float Qmin = (tid<SLICES)? gload(&qnqc[tid]) : 0.f;
    blockReduce2(Qmax,Qmin,sRed);     // syncs also publish sScal/sQnP/sS2p

    if (tid<NSC){
      sQn[tid]=sQnP[tid]+sQnP[tid+128];
      sR2[tid]=sS2p[tid]+sS2p[tid+128]+sLS[tid]-sSP[tid]-sOm[tid];
    }
    const float gamma = sScal[3];

    if (k==NITER){  // ---------------- final: phi + outputs ----------------
      if (tid<NSC){
        const int n=tid;
        float m1=Qmax-gamma*sDM[n], m2=Qmin-gamma*sDm[n];
        float ph=fmaxf(sQn[n],fmaxf(m1,m2));
        sQn[n]=ph;
        if (slice==0) out[76800 + b*NSC + n]=ph;
      }
      float st=0.f, dummy=0.f;
      if (tid<HALF_G){
        const int g=g0+tid;
        const float Pv=sP[tid];
        const float costv=sB[g]*Pv+sC[g];
        st=costv + 0.05f*sB[g]*sRu[tid] + 0.02f*sB[g]*sRd[tid];
        const int o=b*2400 + g*T_ + t_own;
        out[o]=Pv;
        out[19200+o]=sRu[tid];
        out[38400+o]=sRd[tid];
        out[57600+o]=costv;
      }
      blockReduce2(st,dummy,sRed);
      if (tid==0) gstore(&ST1[b*64+slice], st);
      if (slice==0&&tid==0) out[77824+b]=gamma;
      bbar(&BAR[b*16], (++bar_round)*SLICES);
      if (slice==0){
        float pm = (tid<NSC)? sQn[tid] : 0.f;
        float s1 = (tid<SLICES)? gload(&ST1[b*64+tid]) : 0.f;
        blockReduce2(pm,s1,sRed);
        if (tid==0) out[77832+b] = s1 + pm*INVN + eps_in[b]*gamma;
      }
      break;
    }

    // ---- phi subgradient weights (JAX balanced_eq tie rule) + LS/SP update ----
    float g1l=0.f,g2l=0.f,sgl=0.f;
    if (tid<NSC){
      const int n=tid;
      const float Qn=sQn[n];
      const float m1=Qmax-gamma*sDM[n], m2=Qmin-gamma*sDm[n];
      const float inner=fmaxf(m1,m2), ph=fmaxf(Qn,inner);
      const float gQn=(Qn==ph?1.f:0.f)/((inner==ph)?2.f:1.f);
      const float gIn=(inner==ph?1.f:0.f)/((Qn==ph)?2.f:1.f);
      const float gm1=gIn*(m1==inner?1.f:0.f)/((m2==inner)?2.f:1.f);
      const float gm2=gIn*(m2==inner?1.f:0.f)/((m1==inner)?2.f:1.f);
      sGQn[n]=gQn;
      g1l=gm1; g2l=gm2; sgl=gm1*sDM[n]+gm2*sDm[n];
      const float gq=gQn*INVN, r2=sR2[n];
      sLS[n]=fmaxf(sLS[n]-LR*(gq*VOLL+TWO_RHO*r2),0.f);
      sSP[n]=fmaxf(sSP[n]-LR*(gq*VOSP-TWO_RHO*r2),0.f);
    }
    float S1s=g1l,S2s=g2l,Sg=sgl;
    blockReduce3(S1s,S2s,Sg,sRed);   // syncs also publish sGQn + new sLS/sSP

    // ---- pass A: d_up/d_dn update + produce Qn/S2 partials ----
    float accU=0.f, accD=0.f, rtu=0.f, rtd=0.f, ruL=0.f, rdL=0.f;
    if (lane<HALF_G){
      const int g=g0+lane;
      rtu=2.f*sB[g]; rtd=0.5f*sB[g]; ruL=sRu[lane]; rdL=sRd[lane];
    }
    for (int n=wave;n<NSC;n+=4){
      float qv=0.f, sv=0.f;
      if (lane<HALF_G){
        const int idx=n*HALF_G+lane;
        float du=sdU[idx], dd=sdD[idx];
        const float r7=fmaxf(du-ruL,0.f), r8=fmaxf(dd-rdL,0.f);
        accU+=r7; accD+=r8;
        const float gq=sGQn[n]*INVN, r2=sR2[n];
        du=fmaxf(du-LR*(gq*rtu+TWO_RHO*( r2+r7)),0.f);
        dd=fmaxf(dd-LR*(gq*rtd+TWO_RHO*(-r2+r8)),0.f);
        sdU[idx]=du; sdD[idx]=dd;
        qv=rtu*du+rtd*dd; sv=du-dd;
      }
#pragma unroll
      for (int off=32;off;off>>=1){ qv+=__shfl_down(qv,off,64); sv+=__shfl_down(sv,off,64); }
      if (lane==0){
        if (half==0) qv += VOLL*sLS[n]+VOSP*sSP[n];
        gstore(&qnpn[slice*NSC+n],qv);
        gstore(&s2pn[slice*NSC+n],sv);
      }
    }
    sAccU[wave][lane]=accU; sAccD[wave][lane]=accD;
    __syncthreads();

    // ---- pass B: shared row vars (LDS-resident), producer-side partials ----
    const float r3=sScal[0], r4=sScal[1], rP=sScal[2];
    float pQx=0.f,pQn2=0.f,pr3=0.f,pr4=0.f,pPsum=0.f;
    if (tid<HALF_G){
      const int g=g0+tid;
      const float rupS=sAccU[0][tid]+sAccU[1][tid]+sAccU[2][tid]+sAccU[3][tid];
      const float rdnS=sAccD[0][tid]+sAccD[1][tid]+sAccD[2][tid]+sAccD[3][tid];
      const float Pold=sP[tid], ru=sRu[tid], rd=sRd[tid];
      const float duMo=sduM[tid], ddMo=sddM[tid], dumo=sdum[tid], ddmo=sddm[tid];
      const float r5 =fmaxf(Pold+ru-sPmax[g],0.f);
      const float r6 =fmaxf(sPmin[g]-Pold+rd,0.f);
      const float r9 =fmaxf(duMo-ru,0.f), r10=fmaxf(ddMo-rd,0.f);
      const float r11=fmaxf(dumo-ru,0.f), r12=fmaxf(ddmo-rd,0.f);
      const float rampg=sPmax[g];
      float gP=sB[g]+TWO_RHO*(rP+r5-r6);
      if (t_own>0){
        const float dp=Pold-pPm1;
        gP+=TWO_RHO*fmaxf(fabsf(dp)-rampg,0.f)*(dp>=0.f?1.f:-1.f);
      }
      if (t_own<T_-1){
        const float dq=pPp1-Pold;
        gP-=TWO_RHO*fmaxf(fabsf(dq)-rampg,0.f)*(dq>=0.f?1.f:-1.f);
      }
      const float Pn=fminf(fmaxf(Pold-LR*gP,sPmin[g]),sPmax[g]);
      sP[tid]=Pn; gstore(&ppn[t_own*G_+g],Pn);
      const float rtuB=2.f*sB[g], rtdB=0.5f*sB[g];
      sRu[tid]=fmaxf(ru-LR*(0.05f*sB[g]+TWO_RHO*(r5-rupS-r9-r11)),0.f);
      sRd[tid]=fmaxf(rd-LR*(0.02f*sB[g]+TWO_RHO*(r6-rdnS-r10-r12)),0.f);
      const float duMn=fmaxf(duMo-LR*(INVN*S1s*rtuB+TWO_RHO*( r3+r9 )),0.f);
      const float ddMn=fmaxf(ddMo-LR*(INVN*S1s*rtdB+TWO_RHO*(-r3+r10)),0.f);
      const float dumn=fmaxf(dumo-LR*(INVN*S2s*rtuB+TWO_RHO*( r4+r11)),0.f);
      const float ddmn=fmaxf(ddmo-LR*(INVN*S2s*rtdB+TWO_RHO*(-r4+r12)),0.f);
      sduM[tid]=duMn; sddM[tid]=ddMn; sdum[tid]=dumn; sddm[tid]=ddmn;
      pQx=rtuB*duMn+rtdB*ddMn; pQn2=rtuB*dumn+rtdB*ddmn;
      pr3=duMn-ddMn; pr4=dumn-ddmn; pPsum=Pn;
    }
    if (tid==0){
      if (half==0){
        const float LSMn=fmaxf(sLSa-LR*(INVN*S1s*VOLL+TWO_RHO*r3),0.f);
        const float SPMn=fmaxf(sLSb-LR*(INVN*S1s*VOSP-TWO_RHO*r3),0.f);
        sLSa=LSMn; sLSb=SPMn;
        pQx+=VOLL*LSMn+VOSP*SPMn; pr3+=LSMn-SPMn;
      } else {
        const float LSmn=fmaxf(sLSa-LR*(INVN*S2s*VOLL+TWO_RHO*r4),0.f);
        const float SPmn=fmaxf(sLSb-LR*(INVN*S2s*VOSP-TWO_RHO*r4),0.f);
        sLSa=LSmn; sLSb=SPmn;
        pQn2+=VOLL*LSmn+VOSP*SPmn; pr4+=LSmn-SPmn;
      }
    }
    if (slice==0 && tid==63)
      gstore(gamn, fmaxf(gamma-LR*(eps_in[b]-INVN*Sg),0.f));
    if (wave==0){
#pragma unroll
      for (int off=32;off;off>>=1){
        pQx+=__shfl_down(pQx,off,64);  pQn2+=__shfl_down(pQn2,off,64);
        pr3+=__shfl_down(pr3,off,64);  pr4+=__shfl_down(pr4,off,64);
        pPsum+=__shfl_down(pPsum,off,64);
      }
      if (lane==0){
        gstore(&qxpn[slice],pQx); gstore(&qnqn[slice],pQn2);
        gstore(&r3pn[slice],pr3); gstore(&r4pn[slice],pr4);
        gstore(&rppn[slice],pPsum);
      }
    }
    bbar(&BAR[b*16], (++bar_round)*SLICES);
  }
}

extern "C" void kernel_launch(void* const* d_in, const int* in_sizes, int n_in,
                              void* d_out, int out_size, void* d_ws, size_t ws_size,
                              hipStream_t stream) {
  const float* forecast = (const float*)d_in[0];
  const float* omega    = (const float*)d_in[1];
  const float* omin     = (const float*)d_in[2];
  const float* omax     = (const float*)d_in[3];
  const float* eps      = (const float*)d_in[4];
  const float* pmin     = (const float*)d_in[5];
  const float* pmax     = (const float*)d_in[6];
  const float* bG       = (const float*)d_in[7];
  const float* cG       = (const float*)d_in[8];
  float* out = (float*)d_out;
  float* ws  = (float*)d_ws;
  void* args[] = { &forecast, &omega, &omin, &omax, &eps, &pmin, &pmax, &bG, &cG, &out, &ws };
  hipLaunchCooperativeKernel((const void*)dro_kernel, dim3(NBLK), dim3(NTHR),
                             args, 0, stream);
}

// Round 3
// 972.208 us; speedup vs baseline: 1.7363x; 1.1415x over previous
//
#include <hip/hip_runtime.h>
#include <hip/hip_cooperative_groups.h>

namespace cg = cooperative_groups;

#define G_ 100
#define T_ 24
#define NSC 128
#define BATCH 8
#define NITER 40
#define NBLK (BATCH*T_)     // 192 workgroups: one (batch, t) per WG, 1 per CU
#define NTHR 256
#define RS 101              // LDS row stride for [n][g] arrays (conflict-free both mappings)

__device__ __forceinline__ float gload(const float* p){
  return __hip_atomic_load(p, __ATOMIC_RELAXED, __HIP_MEMORY_SCOPE_AGENT);
}
__device__ __forceinline__ void gstore(float* p, float v){
  __hip_atomic_store(p, v, __ATOMIC_RELAXED, __HIP_MEMORY_SCOPE_AGENT);
}
__device__ __forceinline__ unsigned gloadu(const unsigned* p){
  return __hip_atomic_load(p, __ATOMIC_RELAXED, __HIP_MEMORY_SCOPE_AGENT);
}
__device__ __forceinline__ void gstoreu(unsigned* p, unsigned v){
  __hip_atomic_store(p, v, __ATOMIC_RELAXED, __HIP_MEMORY_SCOPE_AGENT);
}

__device__ __forceinline__ void blockReduce2(float& a, float& b, float* sR){
#pragma unroll
  for (int off=32; off; off>>=1){ a+=__shfl_down(a,off,64); b+=__shfl_down(b,off,64); }
  const int w = threadIdx.x>>6;
  __syncthreads();
  if ((threadIdx.x&63)==0){ sR[w]=a; sR[4+w]=b; }
  __syncthreads();
  a = sR[0]+sR[1]+sR[2]+sR[3];
  b = sR[4]+sR[5]+sR[6]+sR[7];
}

__device__ __forceinline__ void blockReduce3(float& a, float& b, float& c, float* sR){
#pragma unroll
  for (int off=32; off; off>>=1){
    a+=__shfl_down(a,off,64); b+=__shfl_down(b,off,64); c+=__shfl_down(c,off,64);
  }
  const int w = threadIdx.x>>6;
  __syncthreads();
  if ((threadIdx.x&63)==0){ sR[w]=a; sR[4+w]=b; sR[8+w]=c; }
  __syncthreads();
  a=sR[0]+sR[1]+sR[2]+sR[3];
  b=sR[4]+sR[5]+sR[6]+sR[7];
  c=sR[8]+sR[9]+sR[10]+sR[11];
}

// each wave polls the 24 per-slice epoch flags of its batch until all >= tgt
__device__ __forceinline__ void waitFlags(const unsigned* fl, unsigned tgt, int lane){
  for (;;){
    unsigned f = (lane < T_) ? gloadu(&fl[lane]) : tgt;
    if (__ballot(f < tgt) == 0ull) break;
    __builtin_amdgcn_s_sleep(1);
  }
  __builtin_amdgcn_fence(__ATOMIC_ACQUIRE, "agent");
}

__global__ __launch_bounds__(NTHR, 1) void dro_kernel(
    const float* __restrict__ forecast, const float* __restrict__ omega,
    const float* __restrict__ om_min, const float* __restrict__ om_max,
    const float* __restrict__ eps_in, const float* __restrict__ pmin_g,
    const float* __restrict__ pmax_g, const float* __restrict__ bG,
    const float* __restrict__ cG, float* __restrict__ out, float* __restrict__ ws)
{
  constexpr float LR=2e-4f, VOLL=1000.f, VOSP=50.f, TWO_RHO=20.f, INVN=1.f/128.f;
  const int blk=blockIdx.x;
  const int b=blk&7;            // round-robin XCD: batch spread, slices of a batch co-XCD-ish
  const int t_own=blk>>3;       // 0..23
  const int tid=threadIdx.x, wave=tid>>6, lane=tid&63;

  __shared__ float sdU[NSC*RS], sdD[NSC*RS];          // [n][g] row stride 101
  __shared__ float sRu[G_], sRd[G_];
  __shared__ float sP[G_], sduM[G_], sddM[G_], sdum[G_], sddm[G_];
  __shared__ float sLS[NSC], sSP[NSC], sOm[NSC];
  __shared__ float sR220[NSC], sGQn[NSC];             // 20*r2 ; gQn/N
  __shared__ float sQn[NSC], sDM[NSC], sDm[NSC], sS2[NSC];
  __shared__ float sQnP[NTHR];
  __shared__ float sB[G_], sPmin[G_], sPmax[G_], sC[G_];
  __shared__ float sAccU[2][G_], sAccD[2][G_];
  __shared__ float sRed[12];
  __shared__ float sScal[8];  // 0..2: r3,r4,rP (current iter); 3..6: LSM,SPM,LSm,SPm

  // ---- ws layout (floats) ----
  float* QNP = ws;                       // [3][B][24][128]
  float* PP  = ws + 73728;               // [3][B][24][128] (first 100 used)
  float* QS  = ws + 147456;              // [3][B][32][2]   (Qmax,Qmin partials)
  float* GAM = ws + 148992;              // [3][16]
  float* ST1 = ws + 149040;              // [B][32]
  unsigned* FLG = (unsigned*)(ws + 149296); // [B][32] monotonic produce-epoch

  const float epsv = eps_in[b];
  const float omaxT = om_max[b*T_ + t_own];
  const float ominT = om_min[b*T_ + t_own];
  const float fctT  = forecast[b*T_ + t_own];
  const unsigned* flB = FLG + b*32;

  // ---------------- init ----------------
  if (tid<G_){
    sB[tid]=bG[tid]; sPmin[tid]=pmin_g[tid]; sPmax[tid]=pmax_g[tid]; sC[tid]=cG[tid];
    sRu[tid]=0.f; sRd[tid]=0.f;
    sduM[tid]=0.f; sddM[tid]=0.f; sdum[tid]=0.f; sddm[tid]=0.f;
  }
  for (int i=tid;i<NSC*RS;i+=NTHR){ sdU[i]=0.f; sdD[i]=0.f; }
  if (tid<NSC){
    const int n=tid;
    sLS[n]=0.f; sSP[n]=0.f; sS2[n]=0.f;
    sOm[n]=omega[(b*NSC+n)*T_+t_own];
    float dM=0.f,dm=0.f;
    for (int t=0;t<T_;++t){
      float o=omega[(b*NSC+n)*T_+t];
      dM+=om_max[b*T_+t]-o; dm+=o-om_min[b*T_+t];
    }
    sDM[n]=dM; sDm[n]=dm;
  }
  if (tid==0){ sScal[3]=0.f; sScal[4]=0.f; sScal[5]=0.f; sScal[6]=0.f; }
  // epoch-0 buffers
  {
    float p0=0.f;
    if (tid<G_){
      p0=0.5f*(sPmin[tid]+sPmax[tid]);
      sP[tid]=p0;
      gstore(&PP[b*3072 + t_own*NSC + tid], p0);
    }
    if (tid<NSC) gstore(&QNP[b*3072 + t_own*NSC + tid], 0.f);
    if (tid<2)   gstore(&QS[b*64 + t_own*2 + tid], 0.f);
    if (t_own==0 && tid==0) gstore(&GAM[b], 0.f);
    float rp=p0, dum0=0.f;
    blockReduce2(rp,dum0,sRed);
    if (tid==0){
      sScal[0]=-omaxT; sScal[1]=-ominT; sScal[2]=rp-fctT;
      gstoreu((unsigned*)&FLG[b*32+t_own], 1u);
    }
  }
  __builtin_amdgcn_fence(__ATOMIC_RELEASE, "agent");
  cg::this_grid().sync();

  for (int k=0;k<=NITER;++k){
    // ---- wait for epoch-k data ----
    waitFlags(flB, (unsigned)(k+1), lane);

    const int rb = k%3, wb = (k+1)%3;
    const float* qnpR = QNP + rb*24576 + b*3072;
    const float* ppR  = PP  + rb*24576 + b*3072;
    const float* qsR  = QS  + rb*512   + b*64;
    float* qnpW = QNP + wb*24576 + b*3072 + t_own*NSC;
    float* ppW  = PP  + wb*24576 + b*3072 + t_own*NSC;
    float* qsW  = QS  + wb*512   + b*64  + t_own*2;

    // ---- early loads ----
    const float gamma = gload(&GAM[rb*16 + b]);
    float pm1=0.f, pp1=0.f;
    if (tid<G_){
      if (t_own>0)     pm1 = gload(&ppR[(t_own-1)*NSC + tid]);
      if (t_own<T_-1)  pp1 = gload(&ppR[(t_own+1)*NSC + tid]);
    }
    {
      const int n = tid&127, sb0 = (tid>>7)*12;
      float q=0.f;
#pragma unroll
      for (int s=0;s<12;++s) q += gload(&qnpR[(sb0+s)*NSC + n]);
      sQnP[tid]=q;
    }
    float Qmax = (tid<T_)? gload(&qsR[tid*2])   : 0.f;
    float Qmin = (tid<T_)? gload(&qsR[tid*2+1]) : 0.f;
    blockReduce2(Qmax,Qmin,sRed);        // its syncs also publish sQnP
    if (tid<NSC) sQn[tid]=sQnP[tid]+sQnP[tid+128];

    if (k==NITER){  // ---------------- final: phi + outputs ----------------
      __syncthreads();
      if (tid<NSC){
        const int n=tid;
        const float m1=Qmax-gamma*sDM[n], m2=Qmin-gamma*sDm[n];
        const float ph=fmaxf(sQn[n],fmaxf(m1,m2));
        sQn[n]=ph;
        if (t_own==0) out[76800 + b*NSC + n]=ph;
      }
      float st=0.f, dum0=0.f;
      if (tid<G_){
        const int g=tid;
        const float Pv=sP[g];
        const float costv=sB[g]*Pv+sC[g];
        st=costv + 0.05f*sB[g]*sRu[g] + 0.02f*sB[g]*sRd[g];
        const int o=b*2400 + g*T_ + t_own;
        out[o]=Pv;
        out[19200+o]=sRu[g];
        out[38400+o]=sRd[g];
        out[57600+o]=costv;
      }
      blockReduce2(st,dum0,sRed);
      if (tid==0) gstore(&ST1[b*32+t_own], st);
      if (t_own==0 && tid==0) out[77824+b]=gamma;
      __builtin_amdgcn_fence(__ATOMIC_RELEASE, "agent");
      __syncthreads();
      if (tid==0) gstoreu((unsigned*)&FLG[b*32+t_own], (unsigned)(NITER+2));
      if (t_own==0){
        waitFlags(flB, (unsigned)(NITER+2), lane);
        float pm = (tid<NSC)? sQn[tid] : 0.f;
        float s1 = (tid<T_)? gload(&ST1[b*32+tid]) : 0.f;
        blockReduce2(pm,s1,sRed);
        if (tid==0) out[77832+b] = s1 + pm*INVN + epsv*gamma;
      }
      break;
    }

    // ---- weights (balanced_eq ties) + LS/SP update ----
    float g1l=0.f,g2l=0.f,sgl=0.f;
    if (tid<NSC){
      const int n=tid;
      const float Qn=sQn[n];
      const float m1=Qmax-gamma*sDM[n], m2=Qmin-gamma*sDm[n];
      const float inner=fmaxf(m1,m2), ph=fmaxf(Qn,inner);
      const float gQn=(Qn==ph?1.f:0.f)/((inner==ph)?2.f:1.f);
      const float gIn=(inner==ph?1.f:0.f)/((Qn==ph)?2.f:1.f);
      const float gm1=gIn*(m1==inner?1.f:0.f)/((m2==inner)?2.f:1.f);
      const float gm2=gIn*(m2==inner?1.f:0.f)/((m1==inner)?2.f:1.f);
      const float gq=gQn*INVN;
      sGQn[n]=gq;
      g1l=gm1; g2l=gm2; sgl=gm1*sDM[n]+gm2*sDm[n];
      const float r2=sS2[n]+sLS[n]-sSP[n]-sOm[n];
      const float r220=TWO_RHO*r2;
      sR220[n]=r220;
      sLS[n]=fmaxf(sLS[n]-LR*(gq*VOLL+r220),0.f);
      sSP[n]=fmaxf(sSP[n]-LR*(gq*VOSP-r220),0.f);
    }
    float S1s=g1l,S2s=g2l,Sg=sgl;
    blockReduce3(S1s,S2s,Sg,sRed);

    // ---- pass A: d_up/d_dn update, accU/accD (g-in-lane, n strided) ----
    {
      const int ghalf=wave&1, nbase=(wave>>1)*64;
      if (lane<50){
        const int g=ghalf*50+lane;
        const float bg=sB[g];
        const float rtu=2.f*bg, rtd=0.5f*bg;
        const float ru=sRu[g], rd=sRd[g];
        float accU=0.f, accD=0.f;
#pragma unroll 4
        for (int j=0;j<64;++j){
          const int n=nbase+j;
          const float gq=sGQn[n];
          const float r220=sR220[n];
          const int idx=n*RS+g;
          float du=sdU[idx], dd=sdD[idx];
          const float r7=fmaxf(du-ru,0.f), r8=fmaxf(dd-rd,0.f);
          accU+=r7; accD+=r8;
          du=fmaxf(du-LR*(gq*rtu+(r220+TWO_RHO*r7)),0.f);
          dd=fmaxf(dd-LR*(gq*rtd+(TWO_RHO*r8-r220)),0.f);
          sdU[idx]=du; sdD[idx]=dd;
        }
        sAccU[wave>>1][g]=accU; sAccD[wave>>1][g]=accD;
      }
    }
    __syncthreads();

    // ---- produce sweep: qv/sv per n (n-in-thread, g contiguous) ----
    {
      const int n=tid>>1, h2=tid&1, gb=h2*50;
      const int row=n*RS+gb;
      float qv=0.f, sv=0.f;
#pragma unroll 5
      for (int j=0;j<50;++j){
        const float du=sdU[row+j], dd=sdD[row+j];
        const float bg=sB[gb+j];
        qv += bg*(2.f*du+0.5f*dd);
        sv += du-dd;
      }
      qv += __shfl_xor(qv,1,64);
      sv += __shfl_xor(sv,1,64);
      if (h2==0){
        sS2[n]=sv;
        qv += VOLL*sLS[n]+VOSP*sSP[n];
        gstore(&qnpW[n], qv);
      }
    }

    // ---- pass B: per-g shared vars (all WG-local) ----
    const float r3=sScal[0], r4=sScal[1], rP=sScal[2];
    float pQx=0.f,pQn2=0.f,pr3=0.f,pr4=0.f,pP=0.f;
    if (tid<G_){
      const int g=tid;
      const float rupS=sAccU[0][g]+sAccU[1][g];
      const float rdnS=sAccD[0][g]+sAccD[1][g];
      const float Pold=sP[g], ru=sRu[g], rd=sRd[g];
      const float duMo=sduM[g], ddMo=sddM[g], dumo=sdum[g], ddmo=sddm[g];
      const float r5 =fmaxf(Pold+ru-sPmax[g],0.f);
      const float r6 =fmaxf(sPmin[g]-Pold+rd,0.f);
      const float r9 =fmaxf(duMo-ru,0.f), r10=fmaxf(ddMo-rd,0.f);
      const float r11=fmaxf(dumo-ru,0.f), r12=fmaxf(ddmo-rd,0.f);
      const float rampg=sPmax[g];
      float gP=sB[g]+TWO_RHO*(rP+r5-r6);
      if (t_own>0){
        const float dp=Pold-pm1;
        gP+=TWO_RHO*fmaxf(fabsf(dp)-rampg,0.f)*(dp>=0.f?1.f:-1.f);
      }
      if (t_own<T_-1){
        const float dq=pp1-Pold;
        gP-=TWO_RHO*fmaxf(fabsf(dq)-rampg,0.f)*(dq>=0.f?1.f:-1.f);
      }
      const float Pn=fminf(fmaxf(Pold-LR*gP,sPmin[g]),sPmax[g]);
      sP[g]=Pn; gstore(&ppW[g],Pn);
      const float rtuB=2.f*sB[g], rtdB=0.5f*sB[g];
      sRu[g]=fmaxf(ru-LR*(0.05f*sB[g]+TWO_RHO*(r5-rupS-r9-r11)),0.f);
      sRd[g]=fmaxf(rd-LR*(0.02f*sB[g]+TWO_RHO*(r6-rdnS-r10-r12)),0.f);
      const float duMn=fmaxf(duMo-LR*(INVN*S1s*rtuB+TWO_RHO*( r3+r9 )),0.f);
      const float ddMn=fmaxf(ddMo-LR*(INVN*S1s*rtdB+TWO_RHO*(-r3+r10)),0.f);
      const float dumn=fmaxf(dumo-LR*(INVN*S2s*rtuB+TWO_RHO*( r4+r11)),0.f);
      const float ddmn=fmaxf(ddmo-LR*(INVN*S2s*rtdB+TWO_RHO*(-r4+r12)),0.f);
      sduM[g]=duMn; sddM[g]=ddMn; sdum[g]=dumn; sddm[g]=ddmn;
      pQx=rtuB*duMn+rtdB*ddMn; pQn2=rtuB*dumn+rtdB*ddmn;
      pr3=duMn-ddMn; pr4=dumn-ddmn; pP=Pn;
    }
    blockReduce3(pQx,pQn2,pr3,sRed);
    blockReduce2(pr4,pP,sRed);
    if (tid==0){
      const float LSMn=fmaxf(sScal[3]-LR*(INVN*S1s*VOLL+TWO_RHO*r3),0.f);
      const float SPMn=fmaxf(sScal[4]-LR*(INVN*S1s*VOSP-TWO_RHO*r3),0.f);
      const float LSmn=fmaxf(sScal[5]-LR*(INVN*S2s*VOLL+TWO_RHO*r4),0.f);
      const float SPmn=fmaxf(sScal[6]-LR*(INVN*S2s*VOSP-TWO_RHO*r4),0.f);
      sScal[3]=LSMn; sScal[4]=SPMn; sScal[5]=LSmn; sScal[6]=SPmn;
      gstore(&qsW[0], pQx + VOLL*LSMn + VOSP*SPMn);
      gstore(&qsW[1], pQn2 + VOLL*LSmn + VOSP*SPmn);
      sScal[0]=pr3 + LSMn - SPMn - omaxT;
      sScal[1]=pr4 + LSmn - SPmn - ominT;
      sScal[2]=pP - fctT;
    }
    if (t_own==0 && tid==64)
      gstore(&GAM[wb*16+b], fmaxf(gamma-LR*(epsv-INVN*Sg),0.f));

    // ---- publish epoch k+1 ----
    __builtin_amdgcn_fence(__ATOMIC_RELEASE, "agent");
    __syncthreads();
    if (tid==0) gstoreu((unsigned*)&FLG[b*32+t_own], (unsigned)(k+2));
  }
}

extern "C" void kernel_launch(void* const* d_in, const int* in_sizes, int n_in,
                              void* d_out, int out_size, void* d_ws, size_t ws_size,
                              hipStream_t stream) {
  const float* forecast = (const float*)d_in[0];
  const float* omega    = (const float*)d_in[1];
  const float* omin     = (const float*)d_in[2];
  const float* omax     = (const float*)d_in[3];
  const float* eps      = (const float*)d_in[4];
  const float* pmin     = (const float*)d_in[5];
  const float* pmax     = (const float*)d_in[6];
  const float* bG       = (const float*)d_in[7];
  const float* cG       = (const float*)d_in[8];
  float* out = (float*)d_out;
  float* ws  = (float*)d_ws;
  void* args[] = { &forecast, &omega, &omin, &omax, &eps, &pmin, &pmax, &bG, &cG, &out, &ws };
  hipLaunchCooperativeKernel((const void*)dro_kernel, dim3(NBLK), dim3(NTHR),
                             args, 0, stream);
}